// Round 19
// baseline (161.249 us; speedup 1.0000x reference)
//
#include <hip/hip_runtime.h>
#include <cstdint>

#define NROWS 50000
#define NCLS  91
#define KPRE  1000
#define NDET  100
#define CAP   4096
#define BIN_OFF 62770u      // bin = (bits>>14) - 62770; scores (0.05,1] -> [1,2254]
#define LOGCLAMP 4.135166556742356f
#define P1BLK 3125          // 3125*256 threads = 50000 rows * 16
#define R2BLK 49            // 49 * 1024 rows >= 50000
#define NFINE 256           // fine bins inside the crossing coarse bucket
#define NU4   6250          // rowmax as uint4: 50000*2B / 16B
#define CPS   3136          // coarse-partial stride (u16) per bucket row
#define CP4   3528          // 9 * 3136/8 uint4 in cpart
#define GCHUNK 128          // greedy: mask rows per LDS chunk
#define IRPB  20            // iou rows per block
#define IBLK  50            // 50*20 = 1000

// ---- workspace layout (bytes) ----
constexpr size_t OFF_CNT     = 0;        // [1]=compact count [2]=iou ticket
constexpr size_t OFF_ROWMAX  = 64;       // 50000*2 (16B-aligned)
constexpr size_t OFF_COMPACT = 100096;   // CAP*8 = 32768
constexpr size_t OFF_SSCORE  = 132864;   // 1024*4
constexpr size_t OFF_SGIDX   = 136960;   // 1024*4
constexpr size_t OFF_SLABEL  = 141056;   // 1024*4
constexpr size_t OFF_BRAW    = 145152;   // 16384
constexpr size_t OFF_BNMS    = 161536;   // 16384
constexpr size_t OFF_MASK    = 177920;   // 1000*16*8 = 128000
constexpr size_t OFF_CPART   = 305920;   // 9*3136*2 = 56448 -> end ~362 KB

__device__ __forceinline__ bool decode_box(int row, int c,
    const float* __restrict__ regr, const float* __restrict__ props,
    float W, float H, float4& b) {
  const float4 rr = *reinterpret_cast<const float4*>(regr + (size_t)row * (NCLS * 4) + c * 4);
  const float4 pp = *reinterpret_cast<const float4*>(props + (size_t)row * 4);
  float pw = pp.z - pp.x, ph = pp.w - pp.y;
  float cx = pp.x + 0.5f * pw, cy = pp.y + 0.5f * ph;
  float dx = rr.x / 10.0f, dy = rr.y / 10.0f;
  float dw = fminf(rr.z / 5.0f, LOGCLAMP);
  float dh = fminf(rr.w / 5.0f, LOGCLAMP);
  float pcx = dx * pw + cx, pcy = dy * ph + cy;
  float ppw = expf(dw) * pw, pph = expf(dh) * ph;
  float x1 = fminf(fmaxf(pcx - 0.5f * ppw, 0.f), W);
  float y1 = fminf(fmaxf(pcy - 0.5f * pph, 0.f), H);
  float x2 = fminf(fmaxf(pcx + 0.5f * ppw, 0.f), W);
  float y2 = fminf(fmaxf(pcy + 0.5f * pph, 0.f), H);
  b = make_float4(x1, y1, x2, y2);
  return (x2 - x1 >= 0.01f) && (y2 - y1 >= 0.01f);
}

__device__ __forceinline__ bool decode_box_v(const float4& rr, const float4& pp,
                                             float W, float H, float4& b) {
  float pw = pp.z - pp.x, ph = pp.w - pp.y;
  float cx = pp.x + 0.5f * pw, cy = pp.y + 0.5f * ph;
  float dx = rr.x / 10.0f, dy = rr.y / 10.0f;
  float dw = fminf(rr.z / 5.0f, LOGCLAMP);
  float dh = fminf(rr.w / 5.0f, LOGCLAMP);
  float pcx = dx * pw + cx, pcy = dy * ph + cy;
  float ppw = expf(dw) * pw, pph = expf(dh) * ph;
  float x1 = fminf(fmaxf(pcx - 0.5f * ppw, 0.f), W);
  float y1 = fminf(fmaxf(pcy - 0.5f * pph, 0.f), H);
  float x2 = fminf(fmaxf(pcx + 0.5f * ppw, 0.f), W);
  float y2 = fminf(fmaxf(pcy + 0.5f * pph, 0.f), H);
  b = make_float4(x1, y1, x2, y2);
  return (x2 - x1 >= 0.01f) && (y2 - y1 >= 0.01f);
}

// K1: 16 threads/row, 6 classes/thread. props prefetched; batched conditional
// regr loads. Emits rowmax + per-block coarse bucket partials. Zeroes cnt[1..2].
__global__ __launch_bounds__(256)
void pass1_kernel(const float* __restrict__ logits,
                  const float* __restrict__ regr,
                  const float* __restrict__ props,
                  const int* __restrict__ p_imh,
                  const int* __restrict__ p_imw,
                  uint16_t* __restrict__ rowmax,
                  uint16_t* __restrict__ cpart,
                  uint32_t* __restrict__ cnt) {
  __shared__ uint32_t lds9[9];
  const int t = threadIdx.x;
  if (blockIdx.x == 0 && t == 0) { cnt[1] = 0; cnt[2] = 0; }
  if (t < 9) lds9[t] = 0;
  __syncthreads();

  const int gt  = blockIdx.x * 256 + t;
  const int row = gt >> 4;
  const int sub = gt & 15;
  const float* lr = logits + (size_t)row * NCLS;
  const float4 pp = *reinterpret_cast<const float4*>(props + (size_t)row * 4);
  const float W = (float)(*p_imw), H = (float)(*p_imh);

  float x[6];
  #pragma unroll
  for (int j = 0; j < 6; ++j) {
    int c = sub + 16 * j;
    x[j] = (c < NCLS) ? lr[c] : -INFINITY;
  }
  float m = x[0];
  #pragma unroll
  for (int j = 1; j < 6; ++j) m = fmaxf(m, x[j]);
  m = fmaxf(m, __shfl_xor(m, 1));
  m = fmaxf(m, __shfl_xor(m, 2));
  m = fmaxf(m, __shfl_xor(m, 4));
  m = fmaxf(m, __shfl_xor(m, 8));
  float e[6]; float s = 0.f;
  #pragma unroll
  for (int j = 0; j < 6; ++j) {
    e[j] = (sub + 16 * j < NCLS) ? expf(x[j] - m) : 0.f;
    s += e[j];
  }
  s += __shfl_xor(s, 1);
  s += __shfl_xor(s, 2);
  s += __shfl_xor(s, 4);
  s += __shfl_xor(s, 8);

  const float4* rr4 = reinterpret_cast<const float4*>(regr) + (size_t)row * NCLS;
  float score[6]; bool ok[6]; float4 rrv[6];
  #pragma unroll
  for (int j = 0; j < 6; ++j) {
    int c = sub + 16 * j;
    score[j] = e[j] / s;
    ok[j] = (c >= 1) && (c < NCLS) && (score[j] > 0.05f);
    rrv[j] = ok[j] ? rr4[c] : make_float4(0.f, 0.f, 0.f, 0.f);
  }
  int maxbin = 0;
  #pragma unroll
  for (int j = 0; j < 6; ++j) {
    if (ok[j]) {
      float4 b;
      if (decode_box_v(rrv[j], pp, W, H, b)) {
        uint32_t bin = (__float_as_uint(score[j]) >> 14) - BIN_OFF;
        if ((int)bin > maxbin) maxbin = (int)bin;
      }
    }
  }
  maxbin = max(maxbin, __shfl_xor(maxbin, 1));
  maxbin = max(maxbin, __shfl_xor(maxbin, 2));
  maxbin = max(maxbin, __shfl_xor(maxbin, 4));
  maxbin = max(maxbin, __shfl_xor(maxbin, 8));
  if (sub == 0) {
    rowmax[row] = (uint16_t)maxbin;
    if (maxbin > 0) atomicAdd(&lds9[maxbin >> 8], 1u);   // bucket 0..8
  }
  __syncthreads();
  if (t < 9) cpart[(size_t)t * CPS + blockIdx.x] = (uint16_t)lds9[t];
  if (blockIdx.x < 9 && t < CPS - P1BLK)
    cpart[(size_t)blockIdx.x * CPS + P1BLK + t] = 0;
}

// K2: 49 blocks x 1024. Coarse from cpart (4 iters), ONE fine pass over
// rowmax (7 iters), exact cut, then refine 1024 rows (op-for-op pass1 math).
__global__ __launch_bounds__(1024)
void refine_kernel(const float* __restrict__ logits,
                   const float* __restrict__ regr,
                   const float* __restrict__ props,
                   const int* __restrict__ p_imh,
                   const int* __restrict__ p_imw,
                   const uint16_t* __restrict__ rowmax,
                   const uint16_t* __restrict__ cpart,
                   uint32_t* __restrict__ cnt,
                   unsigned long long* __restrict__ compact) {
  __shared__ uint32_t fine[NFINE + 1];
  __shared__ uint32_t lds9[9];
  __shared__ uint32_t s_cut;
  const int t = threadIdx.x;
  if (t < 9) lds9[t] = 0;
  if (t < NFINE + 1) fine[t] = 0;
  if (t == 0) s_cut = 0xFFFFFFFFu;
  __syncthreads();

  const uint4* cp4 = reinterpret_cast<const uint4*>(cpart);
  for (int k = t; k < CP4; k += 1024) {
    uint4 v = cp4[k];
    uint32_t ssum = (v.x & 0xffffu) + (v.x >> 16) + (v.y & 0xffffu) + (v.y >> 16) +
                    (v.z & 0xffffu) + (v.z >> 16) + (v.w & 0xffffu) + (v.w >> 16);
    if (ssum) atomicAdd(&lds9[k / 392], ssum);     // 392 uint4 per bucket row
  }
  __syncthreads();
  uint32_t sfx[10];
  sfx[9] = 0;
  #pragma unroll
  for (int q = 8; q >= 0; --q) sfx[q] = sfx[q + 1] + lds9[q];
  const uint32_t total = sfx[0];
  uint32_t cut;
  if (total == 0) {
    cut = 0xFFFFFFFFu;
  } else {
    const uint32_t target = total < (uint32_t)KPRE ? total : (uint32_t)KPRE;
    int Bc = 0;
    uint32_t S_hi = 0;
    #pragma unroll
    for (int q = 8; q >= 0; --q) {
      if (sfx[q] >= target && sfx[q + 1] < target) { Bc = q; S_hi = sfx[q + 1]; }
    }
    const uint4* r128 = reinterpret_cast<const uint4*>(rowmax);
    for (int k = t; k < NU4; k += 1024) {
      uint4 v = r128[k];
      #pragma unroll
      for (int w = 0; w < 4; ++w) {
        uint32_t u = (w == 0) ? v.x : (w == 1) ? v.y : (w == 2) ? v.z : v.w;
        uint32_t a = u & 0xffffu, b = u >> 16;
        if (a && (a >> 8) == (uint32_t)Bc) atomicAdd(&fine[a & 255u], 1u);
        if (b && (b >> 8) == (uint32_t)Bc) atomicAdd(&fine[b & 255u], 1u);
      }
    }
    __syncthreads();
    for (int off = 1; off < NFINE; off <<= 1) {
      uint32_t add = (t < NFINE && t + off < NFINE) ? fine[t + off] : 0;
      __syncthreads();
      if (t < NFINE) fine[t] += add;
      __syncthreads();
    }
    if (t < NFINE) {
      uint32_t hi = S_hi + fine[t];
      uint32_t hin = S_hi + ((t < NFINE - 1) ? fine[t + 1] : 0);
      if (hi >= target && hin < target) s_cut = ((uint32_t)Bc << 8) + (uint32_t)t;
    }
    __syncthreads();
    cut = s_cut;
  }

  const int lane = t & 63;
  const int g16 = lane >> 4;
  const int sub = lane & 15;
  const float W = (float)(*p_imw), H = (float)(*p_imh);
  const int base = blockIdx.x * 1024;
  const int myrow0 = base + t;
  bool qual = (myrow0 < NROWS) && ((uint32_t)rowmax[myrow0] >= cut);
  unsigned long long bm = __ballot(qual);
  if (!bm) return;
  const int waveBase = base + (t & ~63);
  while (bm) {
    int bsel[4];
    #pragma unroll
    for (int k = 0; k < 4; ++k) {
      bsel[k] = bm ? (__ffsll((unsigned long long)bm) - 1) : -1;
      if (bm) bm &= bm - 1;
    }
    const int myb = bsel[g16];
    const int row = waveBase + (myb >= 0 ? myb : 0);
    const float* lr = logits + (size_t)row * NCLS;
    float x[6];
    #pragma unroll
    for (int j = 0; j < 6; ++j) {
      int c = sub + 16 * j;
      x[j] = (c < NCLS) ? lr[c] : -INFINITY;
    }
    float m = x[0];
    #pragma unroll
    for (int j = 1; j < 6; ++j) m = fmaxf(m, x[j]);
    m = fmaxf(m, __shfl_xor(m, 1));
    m = fmaxf(m, __shfl_xor(m, 2));
    m = fmaxf(m, __shfl_xor(m, 4));
    m = fmaxf(m, __shfl_xor(m, 8));
    float e[6]; float s = 0.f;
    #pragma unroll
    for (int j = 0; j < 6; ++j) {
      e[j] = (sub + 16 * j < NCLS) ? expf(x[j] - m) : 0.f;
      s += e[j];
    }
    s += __shfl_xor(s, 1);
    s += __shfl_xor(s, 2);
    s += __shfl_xor(s, 4);
    s += __shfl_xor(s, 8);
    if (myb >= 0) {
      #pragma unroll
      for (int j = 0; j < 6; ++j) {
        int c = sub + 16 * j;
        if (c >= 1 && c < NCLS) {
          float score = e[j] / s;
          if (score > 0.05f) {
            float4 bb;
            if (decode_box(row, c, regr, props, W, H, bb)) {
              uint32_t bits = __float_as_uint(score);
              uint32_t bin = (bits >> 14) - BIN_OFF;
              if (bin >= cut) {
                uint32_t pos = atomicAdd(&cnt[1], 1u);
                if (pos < CAP) {
                  uint32_t gidx = (uint32_t)row * 90u + (uint32_t)(c - 1);
                  compact[pos] = ((unsigned long long)bits << 32) |
                                 (unsigned long long)(0xFFFFFFFFu - gidx);
                }
              }
            }
          }
        }
      }
    }
  }
}

// K3: 1 block x 1024. Rank-based selection (NO bitonic sort): unique 64-bit
// keys -> rank = #{keys greater}; rank<KPRE writes sel/braw/bnms directly.
// Deterministic regardless of compact[] arrival order.
__global__ __launch_bounds__(1024)
void rank_prep_kernel(const unsigned long long* __restrict__ compact,
                      const uint32_t* __restrict__ cnt,
                      const float* __restrict__ regr, const float* __restrict__ props,
                      const int* __restrict__ p_imh, const int* __restrict__ p_imw,
                      float* __restrict__ sel_score, uint32_t* __restrict__ sel_gidx,
                      int* __restrict__ slabel, float4* __restrict__ braw,
                      float4* __restrict__ bnms) {
  __shared__ unsigned long long keys[CAP];
  const int t = threadIdx.x;
  const int M = (int)(cnt[1] < (uint32_t)CAP ? cnt[1] : (uint32_t)CAP);
  for (int i = t; i < M; i += 1024) keys[i] = compact[i];
  __syncthreads();

  const int i0 = t, i1 = t + 1024, i2 = t + 2048, i3 = t + 3072;
  const unsigned long long K_INV = 0xFFFFFFFFFFFFFFFFull;
  unsigned long long k0 = (i0 < M) ? keys[i0] : K_INV;
  unsigned long long k1 = (i1 < M) ? keys[i1] : K_INV;
  unsigned long long k2 = (i2 < M) ? keys[i2] : K_INV;
  unsigned long long k3 = (i3 < M) ? keys[i3] : K_INV;
  int r0 = 0, r1 = 0, r2 = 0, r3 = 0;
  for (int j = 0; j < M; ++j) {
    unsigned long long kj = keys[j];    // lockstep broadcast read
    r0 += (kj > k0); r1 += (kj > k1); r2 += (kj > k2); r3 += (kj > k3);
  }

  const float W = (float)(*p_imw), H = (float)(*p_imh);
  const float offmul = (float)(*p_imw + *p_imh + 2);
  #pragma unroll
  for (int q = 0; q < 4; ++q) {
    const int ii = (q == 0) ? i0 : (q == 1) ? i1 : (q == 2) ? i2 : i3;
    const unsigned long long kk = (q == 0) ? k0 : (q == 1) ? k1 : (q == 2) ? k2 : k3;
    const int rr = (q == 0) ? r0 : (q == 1) ? r1 : (q == 2) ? r2 : r3;
    if (ii < M && rr < KPRE) {
      float sc = __uint_as_float((uint32_t)(kk >> 32));
      uint32_t g = 0xFFFFFFFFu - (uint32_t)kk;
      sel_score[rr] = sc;
      sel_gidx[rr] = g;
      int row = (int)(g / 90u);
      int c   = (int)(g % 90u) + 1;
      float4 b;
      decode_box(row, c, regr, props, W, H, b);
      braw[rr] = b;
      float offv = (float)c * offmul;
      bnms[rr] = make_float4(b.x + offv, b.y + offv, b.z + offv, b.w + offv);
      slabel[rr] = c;
    }
  }
  // neutral fill for ranks in [M, KPRE)
  if (t >= M && t < KPRE) {
    sel_score[t] = -1.f;
    sel_gidx[t] = 0xFFFFFFFFu;
    braw[t] = make_float4(0, 0, 0, 0);
    bnms[t] = make_float4(0, 0, 0, 0);
    slabel[t] = 0;
  }
}

// K4: 50 blocks x 256: 20 mask rows each (4 waves x 4 words); LAST block
// (50-block ticket, ~4 us) runs greedy + output inline.
__global__ __launch_bounds__(256)
void iou_greedy_kernel(const float4* __restrict__ bnms,
                       unsigned long long* __restrict__ mask,
                       const float* __restrict__ sel_score,
                       const int* __restrict__ slabel,
                       const float4* __restrict__ braw,
                       uint32_t* __restrict__ cnt,
                       float* __restrict__ out) {
  __shared__ ulonglong2 buf[2][GCHUNK * 8];       // 32 KB (greedy, winner only)
  __shared__ int kept[NDET];
  __shared__ int s_done;
  __shared__ uint32_t s_prev;
  const int t = threadIdx.x;
  const int lane = t & 63;
  const int wv = t >> 6;

  const int r0 = blockIdx.x * IRPB;
  for (int i = r0; i < r0 + IRPB && i < KPRE; ++i) {
    const float4 bi = bnms[i];
    const float areai = fmaxf(bi.z - bi.x, 0.f) * fmaxf(bi.w - bi.y, 0.f);
    #pragma unroll
    for (int ww = 0; ww < 4; ++ww) {
      int wd = wv * 4 + ww;
      int j = wd * 64 + lane;
      bool bit = false;
      if (j < KPRE && j > i) {
        float4 bj = bnms[j];
        float areaj = fmaxf(bj.z - bj.x, 0.f) * fmaxf(bj.w - bj.y, 0.f);
        float ltx = fmaxf(bi.x, bj.x), lty = fmaxf(bi.y, bj.y);
        float rbx = fminf(bi.z, bj.z), rby = fminf(bi.w, bj.w);
        float iw = fmaxf(rbx - ltx, 0.f), ih = fmaxf(rby - lty, 0.f);
        float inter = iw * ih;
        float iou = inter / (areai + areaj - inter + 1e-7f);
        bit = iou > 0.5f;
      }
      unsigned long long mword = __ballot(bit);
      if (lane == 0) mask[(size_t)i * 16 + wd] = mword;
    }
  }

  // ---- last-block ticket (50 blocks, cheap) -> greedy + output inline ----
  __syncthreads();
  __threadfence();
  if (t == 0) s_prev = atomicAdd(&cnt[2], 1u);
  __syncthreads();
  if (s_prev != (uint32_t)(IBLK - 1)) return;
  __threadfence();

  const ulonglong2* gm2 = reinterpret_cast<const ulonglong2*>(mask);
  constexpr int NCHUNK = (KPRE + GCHUNK - 1) / GCHUNK;   // 8

  unsigned long long kw = 0ull;
  #pragma unroll
  for (int w = 0; w < 16; ++w) {
    int j = w * 64 + lane;
    bool b = (j < KPRE) && (sel_score[j] > 0.f);
    unsigned long long mword = __ballot(b);
    if (lane == w) kw = mword;
  }
  if (t == 0) s_done = 0;

  {
    int rows = (KPRE < GCHUNK) ? KPRE : GCHUNK;
    int n2 = rows * 8;
    for (int k = t; k < n2; k += 256) buf[0][k] = gm2[k];
  }
  __syncthreads();

  int kc = 0;
  for (int c = 0; c < NCHUNK; ++c) {
    if (wv > 0 && c + 1 < NCHUNK) {
      int rows = KPRE - (c + 1) * GCHUNK;
      if (rows > GCHUNK) rows = GCHUNK;
      int n2 = rows * 8;
      size_t gbase = (size_t)(c + 1) * GCHUNK * 8;
      for (int k = t - 64; k < n2; k += 192) buf[(c + 1) & 1][k] = gm2[gbase + k];
    }
    if (wv == 0) {
      const unsigned long long* bb =
          reinterpret_cast<const unsigned long long*>(buf[c & 1]);
      int rows = KPRE - c * GCHUNK;
      if (rows > GCHUNK) rows = GCHUNK;
      unsigned long long curm = (lane < 16) ? bb[lane] : 0ull;
      for (int r = 0; r < rows; ++r) {
        unsigned long long nxt =
            (lane < 16 && r + 1 < rows) ? bb[(r + 1) * 16 + lane] : 0ull;
        int i = c * GCHUNK + r;
        unsigned long long kwv = __shfl(kw, i >> 6);
        if ((kwv >> (i & 63)) & 1ull) {
          if (lane == 0) kept[kc] = i;
          kw &= ~curm;
          ++kc;
          if (kc >= NDET) { if (lane == 0) s_done = 1; break; }
        }
        curm = nxt;
      }
    }
    __syncthreads();
    if (s_done) break;
  }

  if (wv == 0) {
    for (int q = lane; q < NDET; q += 64) {
      if (q < kc) {
        int i = kept[q];
        float4 b = braw[i];
        out[q * 4 + 0] = b.x; out[q * 4 + 1] = b.y;
        out[q * 4 + 2] = b.z; out[q * 4 + 3] = b.w;
        out[4 * NDET + q] = sel_score[i];
        out[5 * NDET + q] = (float)slabel[i];
      } else {
        out[q * 4 + 0] = 0.f; out[q * 4 + 1] = 0.f;
        out[q * 4 + 2] = 0.f; out[q * 4 + 3] = 0.f;
        out[4 * NDET + q] = 0.f;
        out[5 * NDET + q] = 0.f;
      }
    }
  }
}

extern "C" void kernel_launch(void* const* d_in, const int* in_sizes, int n_in,
                              void* d_out, int out_size, void* d_ws, size_t ws_size,
                              hipStream_t stream) {
  const float* logits = (const float*)d_in[0];
  const float* regr   = (const float*)d_in[1];
  const float* props  = (const float*)d_in[2];
  const int*   p_imh  = (const int*)d_in[3];
  const int*   p_imw  = (const int*)d_in[4];
  float* out = (float*)d_out;

  uint8_t* ws = (uint8_t*)d_ws;
  uint32_t* cnt  = (uint32_t*)(ws + OFF_CNT);
  uint16_t* rowmax = (uint16_t*)(ws + OFF_ROWMAX);
  unsigned long long* compact = (unsigned long long*)(ws + OFF_COMPACT);
  float*    sel_score = (float*)(ws + OFF_SSCORE);
  uint32_t* sel_gidx  = (uint32_t*)(ws + OFF_SGIDX);
  int*      slabel    = (int*)(ws + OFF_SLABEL);
  float4*   braw      = (float4*)(ws + OFF_BRAW);
  float4*   bnms      = (float4*)(ws + OFF_BNMS);
  unsigned long long* mask = (unsigned long long*)(ws + OFF_MASK);
  uint16_t* cpart     = (uint16_t*)(ws + OFF_CPART);

  pass1_kernel<<<P1BLK, 256, 0, stream>>>(
      logits, regr, props, p_imh, p_imw, rowmax, cpart, cnt);
  refine_kernel<<<R2BLK, 1024, 0, stream>>>(
      logits, regr, props, p_imh, p_imw, rowmax, cpart, cnt, compact);
  rank_prep_kernel<<<1, 1024, 0, stream>>>(compact, cnt, regr, props, p_imh, p_imw,
                                           sel_score, sel_gidx, slabel, braw, bnms);
  iou_greedy_kernel<<<IBLK, 256, 0, stream>>>(
      bnms, mask, sel_score, slabel, braw, cnt, out);
}

// Round 20
// 93.471 us; speedup vs baseline: 1.7251x; 1.7251x over previous
//
#include <hip/hip_runtime.h>
#include <cstdint>

#define NROWS 50000
#define NCLS  91
#define KPRE  1000
#define NDET  100
#define CAP   4096
#define BIN_OFF 62770u      // bin = (bits>>14) - 62770; scores (0.05,1] -> [1,2254]
#define LOGCLAMP 4.135166556742356f
#define P1BLK 3125          // 3125*256 threads = 50000 rows * 16
#define R2BLK 49            // 49 * 1024 rows >= 50000
#define NFINE 256           // fine bins inside the crossing coarse bucket
#define NU4   6250          // rowmax as uint4: 50000*2B / 16B
#define CPS   3136          // coarse-partial stride (u16) per bucket row
#define CP4   3528          // 9 * 3136/8 uint4 in cpart
#define GCHUNK 128          // greedy: mask rows per LDS chunk
#define RNKB  4             // rank blocks: 4*1024 = CAP keys, 1/thread

// ---- workspace layout (bytes) ----
constexpr size_t OFF_CNT     = 0;        // [1]=compact count
constexpr size_t OFF_ROWMAX  = 64;       // 50000*2 (16B-aligned)
constexpr size_t OFF_COMPACT = 100096;   // CAP*8 = 32768
constexpr size_t OFF_SSCORE  = 132864;   // 1024*4
constexpr size_t OFF_SGIDX   = 136960;   // 1024*4
constexpr size_t OFF_SLABEL  = 141056;   // 1024*4
constexpr size_t OFF_BRAW    = 145152;   // 16384
constexpr size_t OFF_BNMS    = 161536;   // 16384
constexpr size_t OFF_MASK    = 177920;   // 1000*16*8 = 128000
constexpr size_t OFF_CPART   = 305920;   // 9*3136*2 = 56448 -> end ~362 KB

__device__ __forceinline__ bool decode_box(int row, int c,
    const float* __restrict__ regr, const float* __restrict__ props,
    float W, float H, float4& b) {
  const float4 rr = *reinterpret_cast<const float4*>(regr + (size_t)row * (NCLS * 4) + c * 4);
  const float4 pp = *reinterpret_cast<const float4*>(props + (size_t)row * 4);
  float pw = pp.z - pp.x, ph = pp.w - pp.y;
  float cx = pp.x + 0.5f * pw, cy = pp.y + 0.5f * ph;
  float dx = rr.x / 10.0f, dy = rr.y / 10.0f;
  float dw = fminf(rr.z / 5.0f, LOGCLAMP);
  float dh = fminf(rr.w / 5.0f, LOGCLAMP);
  float pcx = dx * pw + cx, pcy = dy * ph + cy;
  float ppw = expf(dw) * pw, pph = expf(dh) * ph;
  float x1 = fminf(fmaxf(pcx - 0.5f * ppw, 0.f), W);
  float y1 = fminf(fmaxf(pcy - 0.5f * pph, 0.f), H);
  float x2 = fminf(fmaxf(pcx + 0.5f * ppw, 0.f), W);
  float y2 = fminf(fmaxf(pcy + 0.5f * pph, 0.f), H);
  b = make_float4(x1, y1, x2, y2);
  return (x2 - x1 >= 0.01f) && (y2 - y1 >= 0.01f);
}

__device__ __forceinline__ bool decode_box_v(const float4& rr, const float4& pp,
                                             float W, float H, float4& b) {
  float pw = pp.z - pp.x, ph = pp.w - pp.y;
  float cx = pp.x + 0.5f * pw, cy = pp.y + 0.5f * ph;
  float dx = rr.x / 10.0f, dy = rr.y / 10.0f;
  float dw = fminf(rr.z / 5.0f, LOGCLAMP);
  float dh = fminf(rr.w / 5.0f, LOGCLAMP);
  float pcx = dx * pw + cx, pcy = dy * ph + cy;
  float ppw = expf(dw) * pw, pph = expf(dh) * ph;
  float x1 = fminf(fmaxf(pcx - 0.5f * ppw, 0.f), W);
  float y1 = fminf(fmaxf(pcy - 0.5f * pph, 0.f), H);
  float x2 = fminf(fmaxf(pcx + 0.5f * ppw, 0.f), W);
  float y2 = fminf(fmaxf(pcy + 0.5f * pph, 0.f), H);
  b = make_float4(x1, y1, x2, y2);
  return (x2 - x1 >= 0.01f) && (y2 - y1 >= 0.01f);
}

// K1: 16 threads/row, 6 classes/thread. props prefetched; batched conditional
// regr loads. Emits rowmax + per-block coarse bucket partials. Zeroes cnt[1].
__global__ __launch_bounds__(256)
void pass1_kernel(const float* __restrict__ logits,
                  const float* __restrict__ regr,
                  const float* __restrict__ props,
                  const int* __restrict__ p_imh,
                  const int* __restrict__ p_imw,
                  uint16_t* __restrict__ rowmax,
                  uint16_t* __restrict__ cpart,
                  uint32_t* __restrict__ cnt) {
  __shared__ uint32_t lds9[9];
  const int t = threadIdx.x;
  if (blockIdx.x == 0 && t == 0) cnt[1] = 0;
  if (t < 9) lds9[t] = 0;
  __syncthreads();

  const int gt  = blockIdx.x * 256 + t;
  const int row = gt >> 4;
  const int sub = gt & 15;
  const float* lr = logits + (size_t)row * NCLS;
  const float4 pp = *reinterpret_cast<const float4*>(props + (size_t)row * 4);
  const float W = (float)(*p_imw), H = (float)(*p_imh);

  float x[6];
  #pragma unroll
  for (int j = 0; j < 6; ++j) {
    int c = sub + 16 * j;
    x[j] = (c < NCLS) ? lr[c] : -INFINITY;
  }
  float m = x[0];
  #pragma unroll
  for (int j = 1; j < 6; ++j) m = fmaxf(m, x[j]);
  m = fmaxf(m, __shfl_xor(m, 1));
  m = fmaxf(m, __shfl_xor(m, 2));
  m = fmaxf(m, __shfl_xor(m, 4));
  m = fmaxf(m, __shfl_xor(m, 8));
  float e[6]; float s = 0.f;
  #pragma unroll
  for (int j = 0; j < 6; ++j) {
    e[j] = (sub + 16 * j < NCLS) ? expf(x[j] - m) : 0.f;
    s += e[j];
  }
  s += __shfl_xor(s, 1);
  s += __shfl_xor(s, 2);
  s += __shfl_xor(s, 4);
  s += __shfl_xor(s, 8);

  const float4* rr4 = reinterpret_cast<const float4*>(regr) + (size_t)row * NCLS;
  float score[6]; bool ok[6]; float4 rrv[6];
  #pragma unroll
  for (int j = 0; j < 6; ++j) {
    int c = sub + 16 * j;
    score[j] = e[j] / s;
    ok[j] = (c >= 1) && (c < NCLS) && (score[j] > 0.05f);
    rrv[j] = ok[j] ? rr4[c] : make_float4(0.f, 0.f, 0.f, 0.f);
  }
  int maxbin = 0;
  #pragma unroll
  for (int j = 0; j < 6; ++j) {
    if (ok[j]) {
      float4 b;
      if (decode_box_v(rrv[j], pp, W, H, b)) {
        uint32_t bin = (__float_as_uint(score[j]) >> 14) - BIN_OFF;
        if ((int)bin > maxbin) maxbin = (int)bin;
      }
    }
  }
  maxbin = max(maxbin, __shfl_xor(maxbin, 1));
  maxbin = max(maxbin, __shfl_xor(maxbin, 2));
  maxbin = max(maxbin, __shfl_xor(maxbin, 4));
  maxbin = max(maxbin, __shfl_xor(maxbin, 8));
  if (sub == 0) {
    rowmax[row] = (uint16_t)maxbin;
    if (maxbin > 0) atomicAdd(&lds9[maxbin >> 8], 1u);   // bucket 0..8
  }
  __syncthreads();
  if (t < 9) cpart[(size_t)t * CPS + blockIdx.x] = (uint16_t)lds9[t];
  if (blockIdx.x < 9 && t < CPS - P1BLK)
    cpart[(size_t)blockIdx.x * CPS + P1BLK + t] = 0;
}

// K2: 49 blocks x 1024. Coarse from cpart (4 iters), ONE fine pass over
// rowmax (7 iters), exact cut, then refine 1024 rows (op-for-op pass1 math).
__global__ __launch_bounds__(1024)
void refine_kernel(const float* __restrict__ logits,
                   const float* __restrict__ regr,
                   const float* __restrict__ props,
                   const int* __restrict__ p_imh,
                   const int* __restrict__ p_imw,
                   const uint16_t* __restrict__ rowmax,
                   const uint16_t* __restrict__ cpart,
                   uint32_t* __restrict__ cnt,
                   unsigned long long* __restrict__ compact) {
  __shared__ uint32_t fine[NFINE + 1];
  __shared__ uint32_t lds9[9];
  __shared__ uint32_t s_cut;
  const int t = threadIdx.x;
  if (t < 9) lds9[t] = 0;
  if (t < NFINE + 1) fine[t] = 0;
  if (t == 0) s_cut = 0xFFFFFFFFu;
  __syncthreads();

  const uint4* cp4 = reinterpret_cast<const uint4*>(cpart);
  for (int k = t; k < CP4; k += 1024) {
    uint4 v = cp4[k];
    uint32_t ssum = (v.x & 0xffffu) + (v.x >> 16) + (v.y & 0xffffu) + (v.y >> 16) +
                    (v.z & 0xffffu) + (v.z >> 16) + (v.w & 0xffffu) + (v.w >> 16);
    if (ssum) atomicAdd(&lds9[k / 392], ssum);     // 392 uint4 per bucket row
  }
  __syncthreads();
  uint32_t sfx[10];
  sfx[9] = 0;
  #pragma unroll
  for (int q = 8; q >= 0; --q) sfx[q] = sfx[q + 1] + lds9[q];
  const uint32_t total = sfx[0];
  uint32_t cut;
  if (total == 0) {
    cut = 0xFFFFFFFFu;
  } else {
    const uint32_t target = total < (uint32_t)KPRE ? total : (uint32_t)KPRE;
    int Bc = 0;
    uint32_t S_hi = 0;
    #pragma unroll
    for (int q = 8; q >= 0; --q) {
      if (sfx[q] >= target && sfx[q + 1] < target) { Bc = q; S_hi = sfx[q + 1]; }
    }
    const uint4* r128 = reinterpret_cast<const uint4*>(rowmax);
    for (int k = t; k < NU4; k += 1024) {
      uint4 v = r128[k];
      #pragma unroll
      for (int w = 0; w < 4; ++w) {
        uint32_t u = (w == 0) ? v.x : (w == 1) ? v.y : (w == 2) ? v.z : v.w;
        uint32_t a = u & 0xffffu, b = u >> 16;
        if (a && (a >> 8) == (uint32_t)Bc) atomicAdd(&fine[a & 255u], 1u);
        if (b && (b >> 8) == (uint32_t)Bc) atomicAdd(&fine[b & 255u], 1u);
      }
    }
    __syncthreads();
    for (int off = 1; off < NFINE; off <<= 1) {
      uint32_t add = (t < NFINE && t + off < NFINE) ? fine[t + off] : 0;
      __syncthreads();
      if (t < NFINE) fine[t] += add;
      __syncthreads();
    }
    if (t < NFINE) {
      uint32_t hi = S_hi + fine[t];
      uint32_t hin = S_hi + ((t < NFINE - 1) ? fine[t + 1] : 0);
      if (hi >= target && hin < target) s_cut = ((uint32_t)Bc << 8) + (uint32_t)t;
    }
    __syncthreads();
    cut = s_cut;
  }

  const int lane = t & 63;
  const int g16 = lane >> 4;
  const int sub = lane & 15;
  const float W = (float)(*p_imw), H = (float)(*p_imh);
  const int base = blockIdx.x * 1024;
  const int myrow0 = base + t;
  bool qual = (myrow0 < NROWS) && ((uint32_t)rowmax[myrow0] >= cut);
  unsigned long long bm = __ballot(qual);
  if (!bm) return;
  const int waveBase = base + (t & ~63);
  while (bm) {
    int bsel[4];
    #pragma unroll
    for (int k = 0; k < 4; ++k) {
      bsel[k] = bm ? (__ffsll((unsigned long long)bm) - 1) : -1;
      if (bm) bm &= bm - 1;
    }
    const int myb = bsel[g16];
    const int row = waveBase + (myb >= 0 ? myb : 0);
    const float* lr = logits + (size_t)row * NCLS;
    float x[6];
    #pragma unroll
    for (int j = 0; j < 6; ++j) {
      int c = sub + 16 * j;
      x[j] = (c < NCLS) ? lr[c] : -INFINITY;
    }
    float m = x[0];
    #pragma unroll
    for (int j = 1; j < 6; ++j) m = fmaxf(m, x[j]);
    m = fmaxf(m, __shfl_xor(m, 1));
    m = fmaxf(m, __shfl_xor(m, 2));
    m = fmaxf(m, __shfl_xor(m, 4));
    m = fmaxf(m, __shfl_xor(m, 8));
    float e[6]; float s = 0.f;
    #pragma unroll
    for (int j = 0; j < 6; ++j) {
      e[j] = (sub + 16 * j < NCLS) ? expf(x[j] - m) : 0.f;
      s += e[j];
    }
    s += __shfl_xor(s, 1);
    s += __shfl_xor(s, 2);
    s += __shfl_xor(s, 4);
    s += __shfl_xor(s, 8);
    if (myb >= 0) {
      #pragma unroll
      for (int j = 0; j < 6; ++j) {
        int c = sub + 16 * j;
        if (c >= 1 && c < NCLS) {
          float score = e[j] / s;
          if (score > 0.05f) {
            float4 bb;
            if (decode_box(row, c, regr, props, W, H, bb)) {
              uint32_t bits = __float_as_uint(score);
              uint32_t bin = (bits >> 14) - BIN_OFF;
              if (bin >= cut) {
                uint32_t pos = atomicAdd(&cnt[1], 1u);
                if (pos < CAP) {
                  uint32_t gidx = (uint32_t)row * 90u + (uint32_t)(c - 1);
                  compact[pos] = ((unsigned long long)bits << 32) |
                                 (unsigned long long)(0xFFFFFFFFu - gidx);
                }
              }
            }
          }
        }
      }
    }
  }
}

// K3: 4 blocks x 1024. Rank-based selection: block b ranks keys
// [b*1024, b*1024+1023] against all M keys (LDS staged, unroll-16 loop,
// 16 waves of TLP). Unique keys -> exact ranks; deterministic output.
__global__ __launch_bounds__(1024)
void rank_prep_kernel(const unsigned long long* __restrict__ compact,
                      const uint32_t* __restrict__ cnt,
                      const float* __restrict__ regr, const float* __restrict__ props,
                      const int* __restrict__ p_imh, const int* __restrict__ p_imw,
                      float* __restrict__ sel_score, uint32_t* __restrict__ sel_gidx,
                      int* __restrict__ slabel, float4* __restrict__ braw,
                      float4* __restrict__ bnms) {
  __shared__ unsigned long long keys[CAP];
  const int t = threadIdx.x;
  const int M = (int)(cnt[1] < (uint32_t)CAP ? cnt[1] : (uint32_t)CAP);
  for (int i = t; i < M; i += 1024) keys[i] = compact[i];
  __syncthreads();

  const int ii = blockIdx.x * 1024 + t;
  const unsigned long long kk = (ii < M) ? keys[ii] : 0xFFFFFFFFFFFFFFFFull;
  int r = 0;
  int j = 0;
  const int M16 = M & ~15;
  #pragma unroll 1
  for (; j < M16; j += 16) {
    int acc = 0;
    #pragma unroll
    for (int u = 0; u < 16; ++u) acc += (keys[j + u] > kk);
    r += acc;
  }
  for (; j < M; ++j) r += (keys[j] > kk);

  const float W = (float)(*p_imw), H = (float)(*p_imh);
  const float offmul = (float)(*p_imw + *p_imh + 2);
  if (ii < M && r < KPRE) {
    float sc = __uint_as_float((uint32_t)(kk >> 32));
    uint32_t g = 0xFFFFFFFFu - (uint32_t)kk;
    sel_score[r] = sc;
    sel_gidx[r] = g;
    int row = (int)(g / 90u);
    int c   = (int)(g % 90u) + 1;
    float4 b;
    decode_box(row, c, regr, props, W, H, b);
    braw[r] = b;
    float offv = (float)c * offmul;
    bnms[r] = make_float4(b.x + offv, b.y + offv, b.z + offv, b.w + offv);
    slabel[r] = c;
  }
  // neutral fill for ranks in [M, KPRE) (block 0 only; rank slots >= M unused)
  if (blockIdx.x == 0 && t >= M && t < KPRE) {
    sel_score[t] = -1.f;
    sel_gidx[t] = 0xFFFFFFFFu;
    braw[t] = make_float4(0, 0, 0, 0);
    bnms[t] = make_float4(0, 0, 0, 0);
    slabel[t] = 0;
  }
}

// K4: 1000 blocks x 256: 4 waves x 4 mask-words each.
__global__ __launch_bounds__(256)
void iou_kernel(const float4* __restrict__ bnms, unsigned long long* __restrict__ mask) {
  const int i = blockIdx.x;
  const int lane = threadIdx.x & 63;
  const int wv = threadIdx.x >> 6;
  const float4 bi = bnms[i];
  const float areai = fmaxf(bi.z - bi.x, 0.f) * fmaxf(bi.w - bi.y, 0.f);
  #pragma unroll
  for (int ww = 0; ww < 4; ++ww) {
    int wd = wv * 4 + ww;
    int j = wd * 64 + lane;
    bool bit = false;
    if (j < KPRE && j > i) {
      float4 bj = bnms[j];
      float areaj = fmaxf(bj.z - bj.x, 0.f) * fmaxf(bj.w - bj.y, 0.f);
      float ltx = fmaxf(bi.x, bj.x), lty = fmaxf(bi.y, bj.y);
      float rbx = fminf(bi.z, bj.z), rby = fminf(bi.w, bj.w);
      float iw = fmaxf(rbx - ltx, 0.f), ih = fmaxf(rby - lty, 0.f);
      float inter = iw * ih;
      float iou = inter / (areai + areaj - inter + 1e-7f);
      bit = iou > 0.5f;
    }
    unsigned long long mword = __ballot(bit);
    if (lane == 0) mask[(size_t)i * 16 + wd] = mword;
  }
}

// K5: greedy NMS: wave 0 scans from LDS; waves 1-3 prefetch next chunk.
__global__ __launch_bounds__(256)
void greedy_kernel(const unsigned long long* __restrict__ mask,
                   const float* __restrict__ sel_score,
                   const int* __restrict__ slabel,
                   const float4* __restrict__ braw,
                   float* __restrict__ out) {
  __shared__ ulonglong2 buf[2][GCHUNK * 8];       // 2 x 16 KB
  __shared__ int kept[NDET];
  __shared__ int s_done;
  const int t = threadIdx.x;
  const int lane = t & 63;
  const int wv = t >> 6;
  const ulonglong2* gm2 = reinterpret_cast<const ulonglong2*>(mask);
  constexpr int NCHUNK = (KPRE + GCHUNK - 1) / GCHUNK;   // 8

  unsigned long long kw = 0ull;
  #pragma unroll
  for (int w = 0; w < 16; ++w) {
    int j = w * 64 + lane;
    bool b = (j < KPRE) && (sel_score[j] > 0.f);
    unsigned long long mword = __ballot(b);
    if (lane == w) kw = mword;
  }
  if (t == 0) s_done = 0;

  {
    int rows = (KPRE < GCHUNK) ? KPRE : GCHUNK;
    int n2 = rows * 8;
    for (int k = t; k < n2; k += 256) buf[0][k] = gm2[k];
  }
  __syncthreads();

  int kc = 0;
  for (int c = 0; c < NCHUNK; ++c) {
    if (wv > 0 && c + 1 < NCHUNK) {
      int rows = KPRE - (c + 1) * GCHUNK;
      if (rows > GCHUNK) rows = GCHUNK;
      int n2 = rows * 8;
      size_t gbase = (size_t)(c + 1) * GCHUNK * 8;
      for (int k = t - 64; k < n2; k += 192) buf[(c + 1) & 1][k] = gm2[gbase + k];
    }
    if (wv == 0) {
      const unsigned long long* bb =
          reinterpret_cast<const unsigned long long*>(buf[c & 1]);
      int rows = KPRE - c * GCHUNK;
      if (rows > GCHUNK) rows = GCHUNK;
      unsigned long long curm = (lane < 16) ? bb[lane] : 0ull;
      for (int r = 0; r < rows; ++r) {
        unsigned long long nxt =
            (lane < 16 && r + 1 < rows) ? bb[(r + 1) * 16 + lane] : 0ull;
        int i = c * GCHUNK + r;
        unsigned long long kwv = __shfl(kw, i >> 6);
        if ((kwv >> (i & 63)) & 1ull) {
          if (lane == 0) kept[kc] = i;
          kw &= ~curm;
          ++kc;
          if (kc >= NDET) { if (lane == 0) s_done = 1; break; }
        }
        curm = nxt;
      }
    }
    __syncthreads();
    if (s_done) break;
  }

  if (wv == 0) {
    for (int q = lane; q < NDET; q += 64) {
      if (q < kc) {
        int i = kept[q];
        float4 b = braw[i];
        out[q * 4 + 0] = b.x; out[q * 4 + 1] = b.y;
        out[q * 4 + 2] = b.z; out[q * 4 + 3] = b.w;
        out[4 * NDET + q] = sel_score[i];
        out[5 * NDET + q] = (float)slabel[i];
      } else {
        out[q * 4 + 0] = 0.f; out[q * 4 + 1] = 0.f;
        out[q * 4 + 2] = 0.f; out[q * 4 + 3] = 0.f;
        out[4 * NDET + q] = 0.f;
        out[5 * NDET + q] = 0.f;
      }
    }
  }
}

extern "C" void kernel_launch(void* const* d_in, const int* in_sizes, int n_in,
                              void* d_out, int out_size, void* d_ws, size_t ws_size,
                              hipStream_t stream) {
  const float* logits = (const float*)d_in[0];
  const float* regr   = (const float*)d_in[1];
  const float* props  = (const float*)d_in[2];
  const int*   p_imh  = (const int*)d_in[3];
  const int*   p_imw  = (const int*)d_in[4];
  float* out = (float*)d_out;

  uint8_t* ws = (uint8_t*)d_ws;
  uint32_t* cnt  = (uint32_t*)(ws + OFF_CNT);
  uint16_t* rowmax = (uint16_t*)(ws + OFF_ROWMAX);
  unsigned long long* compact = (unsigned long long*)(ws + OFF_COMPACT);
  float*    sel_score = (float*)(ws + OFF_SSCORE);
  uint32_t* sel_gidx  = (uint32_t*)(ws + OFF_SGIDX);
  int*      slabel    = (int*)(ws + OFF_SLABEL);
  float4*   braw      = (float4*)(ws + OFF_BRAW);
  float4*   bnms      = (float4*)(ws + OFF_BNMS);
  unsigned long long* mask = (unsigned long long*)(ws + OFF_MASK);
  uint16_t* cpart     = (uint16_t*)(ws + OFF_CPART);

  pass1_kernel<<<P1BLK, 256, 0, stream>>>(
      logits, regr, props, p_imh, p_imw, rowmax, cpart, cnt);
  refine_kernel<<<R2BLK, 1024, 0, stream>>>(
      logits, regr, props, p_imh, p_imw, rowmax, cpart, cnt, compact);
  rank_prep_kernel<<<RNKB, 1024, 0, stream>>>(compact, cnt, regr, props, p_imh, p_imw,
                                              sel_score, sel_gidx, slabel, braw, bnms);
  iou_kernel<<<KPRE, 256, 0, stream>>>(bnms, mask);
  greedy_kernel<<<1, 256, 0, stream>>>(mask, sel_score, slabel, braw, out);
}

// Round 21
// 92.138 us; speedup vs baseline: 1.7501x; 1.0145x over previous
//
#include <hip/hip_runtime.h>
#include <cstdint>

#define NROWS 50000
#define NCLS  91
#define KPRE  1000
#define NDET  100
#define CAP   4096
#define BIN_OFF 62770u      // bin = (bits>>14) - 62770; scores (0.05,1] -> [1,2254]
#define LOGCLAMP 4.135166556742356f
#define P1BLK 3125          // 3125*256 threads = 50000 rows * 16
#define R2BLK 196           // 196 blocks * 256 rows = 50176 >= 50000
#define R2ROWS 256          // rows per refine block
#define NFINE 256           // fine bins inside the crossing coarse bucket
#define NU4   6250          // rowmax as uint4: 50000*2B / 16B
#define CPS   3136          // coarse-partial stride (u16) per bucket row
#define CP4   3528          // 9 * 3136/8 uint4 in cpart
#define GCHUNK 128          // greedy: mask rows per LDS chunk
#define RNKB  4             // rank blocks: 4*1024 = CAP keys, 1/thread

// ---- workspace layout (bytes) ----
constexpr size_t OFF_CNT     = 0;        // [1]=compact count
constexpr size_t OFF_ROWMAX  = 64;       // 50000*2 (16B-aligned)
constexpr size_t OFF_COMPACT = 100096;   // CAP*8 = 32768
constexpr size_t OFF_SSCORE  = 132864;   // 1024*4
constexpr size_t OFF_SGIDX   = 136960;   // 1024*4
constexpr size_t OFF_SLABEL  = 141056;   // 1024*4
constexpr size_t OFF_BRAW    = 145152;   // 16384
constexpr size_t OFF_BNMS    = 161536;   // 16384
constexpr size_t OFF_MASK    = 177920;   // 1000*16*8 = 128000
constexpr size_t OFF_CPART   = 305920;   // 9*3136*2 = 56448 -> end ~362 KB

__device__ __forceinline__ bool decode_box(int row, int c,
    const float* __restrict__ regr, const float* __restrict__ props,
    float W, float H, float4& b) {
  const float4 rr = *reinterpret_cast<const float4*>(regr + (size_t)row * (NCLS * 4) + c * 4);
  const float4 pp = *reinterpret_cast<const float4*>(props + (size_t)row * 4);
  float pw = pp.z - pp.x, ph = pp.w - pp.y;
  float cx = pp.x + 0.5f * pw, cy = pp.y + 0.5f * ph;
  float dx = rr.x / 10.0f, dy = rr.y / 10.0f;
  float dw = fminf(rr.z / 5.0f, LOGCLAMP);
  float dh = fminf(rr.w / 5.0f, LOGCLAMP);
  float pcx = dx * pw + cx, pcy = dy * ph + cy;
  float ppw = expf(dw) * pw, pph = expf(dh) * ph;
  float x1 = fminf(fmaxf(pcx - 0.5f * ppw, 0.f), W);
  float y1 = fminf(fmaxf(pcy - 0.5f * pph, 0.f), H);
  float x2 = fminf(fmaxf(pcx + 0.5f * ppw, 0.f), W);
  float y2 = fminf(fmaxf(pcy + 0.5f * pph, 0.f), H);
  b = make_float4(x1, y1, x2, y2);
  return (x2 - x1 >= 0.01f) && (y2 - y1 >= 0.01f);
}

__device__ __forceinline__ bool decode_box_v(const float4& rr, const float4& pp,
                                             float W, float H, float4& b) {
  float pw = pp.z - pp.x, ph = pp.w - pp.y;
  float cx = pp.x + 0.5f * pw, cy = pp.y + 0.5f * ph;
  float dx = rr.x / 10.0f, dy = rr.y / 10.0f;
  float dw = fminf(rr.z / 5.0f, LOGCLAMP);
  float dh = fminf(rr.w / 5.0f, LOGCLAMP);
  float pcx = dx * pw + cx, pcy = dy * ph + cy;
  float ppw = expf(dw) * pw, pph = expf(dh) * ph;
  float x1 = fminf(fmaxf(pcx - 0.5f * ppw, 0.f), W);
  float y1 = fminf(fmaxf(pcy - 0.5f * pph, 0.f), H);
  float x2 = fminf(fmaxf(pcx + 0.5f * ppw, 0.f), W);
  float y2 = fminf(fmaxf(pcy + 0.5f * pph, 0.f), H);
  b = make_float4(x1, y1, x2, y2);
  return (x2 - x1 >= 0.01f) && (y2 - y1 >= 0.01f);
}

// K1: 16 threads/row, 6 classes/thread. props prefetched; batched conditional
// regr loads. Emits rowmax + per-block coarse bucket partials. Zeroes cnt[1].
__global__ __launch_bounds__(256)
void pass1_kernel(const float* __restrict__ logits,
                  const float* __restrict__ regr,
                  const float* __restrict__ props,
                  const int* __restrict__ p_imh,
                  const int* __restrict__ p_imw,
                  uint16_t* __restrict__ rowmax,
                  uint16_t* __restrict__ cpart,
                  uint32_t* __restrict__ cnt) {
  __shared__ uint32_t lds9[9];
  const int t = threadIdx.x;
  if (blockIdx.x == 0 && t == 0) cnt[1] = 0;
  if (t < 9) lds9[t] = 0;
  __syncthreads();

  const int gt  = blockIdx.x * 256 + t;
  const int row = gt >> 4;
  const int sub = gt & 15;
  const float* lr = logits + (size_t)row * NCLS;
  const float4 pp = *reinterpret_cast<const float4*>(props + (size_t)row * 4);
  const float W = (float)(*p_imw), H = (float)(*p_imh);

  float x[6];
  #pragma unroll
  for (int j = 0; j < 6; ++j) {
    int c = sub + 16 * j;
    x[j] = (c < NCLS) ? lr[c] : -INFINITY;
  }
  float m = x[0];
  #pragma unroll
  for (int j = 1; j < 6; ++j) m = fmaxf(m, x[j]);
  m = fmaxf(m, __shfl_xor(m, 1));
  m = fmaxf(m, __shfl_xor(m, 2));
  m = fmaxf(m, __shfl_xor(m, 4));
  m = fmaxf(m, __shfl_xor(m, 8));
  float e[6]; float s = 0.f;
  #pragma unroll
  for (int j = 0; j < 6; ++j) {
    e[j] = (sub + 16 * j < NCLS) ? expf(x[j] - m) : 0.f;
    s += e[j];
  }
  s += __shfl_xor(s, 1);
  s += __shfl_xor(s, 2);
  s += __shfl_xor(s, 4);
  s += __shfl_xor(s, 8);

  const float4* rr4 = reinterpret_cast<const float4*>(regr) + (size_t)row * NCLS;
  float score[6]; bool ok[6]; float4 rrv[6];
  #pragma unroll
  for (int j = 0; j < 6; ++j) {
    int c = sub + 16 * j;
    score[j] = e[j] / s;
    ok[j] = (c >= 1) && (c < NCLS) && (score[j] > 0.05f);
    rrv[j] = ok[j] ? rr4[c] : make_float4(0.f, 0.f, 0.f, 0.f);
  }
  int maxbin = 0;
  #pragma unroll
  for (int j = 0; j < 6; ++j) {
    if (ok[j]) {
      float4 b;
      if (decode_box_v(rrv[j], pp, W, H, b)) {
        uint32_t bin = (__float_as_uint(score[j]) >> 14) - BIN_OFF;
        if ((int)bin > maxbin) maxbin = (int)bin;
      }
    }
  }
  maxbin = max(maxbin, __shfl_xor(maxbin, 1));
  maxbin = max(maxbin, __shfl_xor(maxbin, 2));
  maxbin = max(maxbin, __shfl_xor(maxbin, 4));
  maxbin = max(maxbin, __shfl_xor(maxbin, 8));
  if (sub == 0) {
    rowmax[row] = (uint16_t)maxbin;
    if (maxbin > 0) atomicAdd(&lds9[maxbin >> 8], 1u);   // bucket 0..8
  }
  __syncthreads();
  if (t < 9) cpart[(size_t)t * CPS + blockIdx.x] = (uint16_t)lds9[t];
  if (blockIdx.x < 9 && t < CPS - P1BLK)
    cpart[(size_t)blockIdx.x * CPS + P1BLK + t] = 0;
}

// K2: 196 blocks x 1024 (256 rows each). Coarse from cpart, ONE fine pass
// over rowmax, exact cut (redundant per block), refine rows. 4x the CU
// coverage of the 49-block version -> shorter latency-bound chains.
__global__ __launch_bounds__(1024)
void refine_kernel(const float* __restrict__ logits,
                   const float* __restrict__ regr,
                   const float* __restrict__ props,
                   const int* __restrict__ p_imh,
                   const int* __restrict__ p_imw,
                   const uint16_t* __restrict__ rowmax,
                   const uint16_t* __restrict__ cpart,
                   uint32_t* __restrict__ cnt,
                   unsigned long long* __restrict__ compact) {
  __shared__ uint32_t fine[NFINE + 1];
  __shared__ uint32_t lds9[9];
  __shared__ uint32_t s_cut;
  const int t = threadIdx.x;
  if (t < 9) lds9[t] = 0;
  if (t < NFINE + 1) fine[t] = 0;
  if (t == 0) s_cut = 0xFFFFFFFFu;
  __syncthreads();

  const uint4* cp4 = reinterpret_cast<const uint4*>(cpart);
  for (int k = t; k < CP4; k += 1024) {
    uint4 v = cp4[k];
    uint32_t ssum = (v.x & 0xffffu) + (v.x >> 16) + (v.y & 0xffffu) + (v.y >> 16) +
                    (v.z & 0xffffu) + (v.z >> 16) + (v.w & 0xffffu) + (v.w >> 16);
    if (ssum) atomicAdd(&lds9[k / 392], ssum);     // 392 uint4 per bucket row
  }
  __syncthreads();
  uint32_t sfx[10];
  sfx[9] = 0;
  #pragma unroll
  for (int q = 8; q >= 0; --q) sfx[q] = sfx[q + 1] + lds9[q];
  const uint32_t total = sfx[0];
  uint32_t cut;
  if (total == 0) {
    cut = 0xFFFFFFFFu;
  } else {
    const uint32_t target = total < (uint32_t)KPRE ? total : (uint32_t)KPRE;
    int Bc = 0;
    uint32_t S_hi = 0;
    #pragma unroll
    for (int q = 8; q >= 0; --q) {
      if (sfx[q] >= target && sfx[q + 1] < target) { Bc = q; S_hi = sfx[q + 1]; }
    }
    const uint4* r128 = reinterpret_cast<const uint4*>(rowmax);
    for (int k = t; k < NU4; k += 1024) {
      uint4 v = r128[k];
      #pragma unroll
      for (int w = 0; w < 4; ++w) {
        uint32_t u = (w == 0) ? v.x : (w == 1) ? v.y : (w == 2) ? v.z : v.w;
        uint32_t a = u & 0xffffu, b = u >> 16;
        if (a && (a >> 8) == (uint32_t)Bc) atomicAdd(&fine[a & 255u], 1u);
        if (b && (b >> 8) == (uint32_t)Bc) atomicAdd(&fine[b & 255u], 1u);
      }
    }
    __syncthreads();
    for (int off = 1; off < NFINE; off <<= 1) {
      uint32_t add = (t < NFINE && t + off < NFINE) ? fine[t + off] : 0;
      __syncthreads();
      if (t < NFINE) fine[t] += add;
      __syncthreads();
    }
    if (t < NFINE) {
      uint32_t hi = S_hi + fine[t];
      uint32_t hin = S_hi + ((t < NFINE - 1) ? fine[t + 1] : 0);
      if (hi >= target && hin < target) s_cut = ((uint32_t)Bc << 8) + (uint32_t)t;
    }
    __syncthreads();
    cut = s_cut;
  }

  // ---- refine this block's 256 rows (threads 0..255; op-for-op pass1 math) ----
  const int lane = t & 63;
  const int g16 = lane >> 4;
  const int sub = lane & 15;
  const float W = (float)(*p_imw), H = (float)(*p_imh);
  const int base = blockIdx.x * R2ROWS;
  const int myrow0 = base + t;
  bool qual = (t < R2ROWS) && (myrow0 < NROWS) && ((uint32_t)rowmax[myrow0] >= cut);
  unsigned long long bm = __ballot(qual);
  if (!bm) return;
  const int waveBase = base + (t & ~63);
  while (bm) {
    int bsel[4];
    #pragma unroll
    for (int k = 0; k < 4; ++k) {
      bsel[k] = bm ? (__ffsll((unsigned long long)bm) - 1) : -1;
      if (bm) bm &= bm - 1;
    }
    const int myb = bsel[g16];
    const int row = waveBase + (myb >= 0 ? myb : 0);
    const float* lr = logits + (size_t)row * NCLS;
    float x[6];
    #pragma unroll
    for (int j = 0; j < 6; ++j) {
      int c = sub + 16 * j;
      x[j] = (c < NCLS) ? lr[c] : -INFINITY;
    }
    float m = x[0];
    #pragma unroll
    for (int j = 1; j < 6; ++j) m = fmaxf(m, x[j]);
    m = fmaxf(m, __shfl_xor(m, 1));
    m = fmaxf(m, __shfl_xor(m, 2));
    m = fmaxf(m, __shfl_xor(m, 4));
    m = fmaxf(m, __shfl_xor(m, 8));
    float e[6]; float s = 0.f;
    #pragma unroll
    for (int j = 0; j < 6; ++j) {
      e[j] = (sub + 16 * j < NCLS) ? expf(x[j] - m) : 0.f;
      s += e[j];
    }
    s += __shfl_xor(s, 1);
    s += __shfl_xor(s, 2);
    s += __shfl_xor(s, 4);
    s += __shfl_xor(s, 8);
    if (myb >= 0) {
      #pragma unroll
      for (int j = 0; j < 6; ++j) {
        int c = sub + 16 * j;
        if (c >= 1 && c < NCLS) {
          float score = e[j] / s;
          if (score > 0.05f) {
            float4 bb;
            if (decode_box(row, c, regr, props, W, H, bb)) {
              uint32_t bits = __float_as_uint(score);
              uint32_t bin = (bits >> 14) - BIN_OFF;
              if (bin >= cut) {
                uint32_t pos = atomicAdd(&cnt[1], 1u);
                if (pos < CAP) {
                  uint32_t gidx = (uint32_t)row * 90u + (uint32_t)(c - 1);
                  compact[pos] = ((unsigned long long)bits << 32) |
                                 (unsigned long long)(0xFFFFFFFFu - gidx);
                }
              }
            }
          }
        }
      }
    }
  }
}

// K3: 4 blocks x 1024. Rank-based selection (unroll-16 LDS broadcast loop).
__global__ __launch_bounds__(1024)
void rank_prep_kernel(const unsigned long long* __restrict__ compact,
                      const uint32_t* __restrict__ cnt,
                      const float* __restrict__ regr, const float* __restrict__ props,
                      const int* __restrict__ p_imh, const int* __restrict__ p_imw,
                      float* __restrict__ sel_score, uint32_t* __restrict__ sel_gidx,
                      int* __restrict__ slabel, float4* __restrict__ braw,
                      float4* __restrict__ bnms) {
  __shared__ unsigned long long keys[CAP];
  const int t = threadIdx.x;
  const int M = (int)(cnt[1] < (uint32_t)CAP ? cnt[1] : (uint32_t)CAP);
  for (int i = t; i < M; i += 1024) keys[i] = compact[i];
  __syncthreads();

  const int ii = blockIdx.x * 1024 + t;
  const unsigned long long kk = (ii < M) ? keys[ii] : 0xFFFFFFFFFFFFFFFFull;
  int r = 0;
  int j = 0;
  const int M16 = M & ~15;
  #pragma unroll 1
  for (; j < M16; j += 16) {
    int acc = 0;
    #pragma unroll
    for (int u = 0; u < 16; ++u) acc += (keys[j + u] > kk);
    r += acc;
  }
  for (; j < M; ++j) r += (keys[j] > kk);

  const float W = (float)(*p_imw), H = (float)(*p_imh);
  const float offmul = (float)(*p_imw + *p_imh + 2);
  if (ii < M && r < KPRE) {
    float sc = __uint_as_float((uint32_t)(kk >> 32));
    uint32_t g = 0xFFFFFFFFu - (uint32_t)kk;
    sel_score[r] = sc;
    sel_gidx[r] = g;
    int row = (int)(g / 90u);
    int c   = (int)(g % 90u) + 1;
    float4 b;
    decode_box(row, c, regr, props, W, H, b);
    braw[r] = b;
    float offv = (float)c * offmul;
    bnms[r] = make_float4(b.x + offv, b.y + offv, b.z + offv, b.w + offv);
    slabel[r] = c;
  }
  if (blockIdx.x == 0 && t >= M && t < KPRE) {
    sel_score[t] = -1.f;
    sel_gidx[t] = 0xFFFFFFFFu;
    braw[t] = make_float4(0, 0, 0, 0);
    bnms[t] = make_float4(0, 0, 0, 0);
    slabel[t] = 0;
  }
}

// K4: 1000 blocks x 256: 4 waves x 4 mask-words each.
__global__ __launch_bounds__(256)
void iou_kernel(const float4* __restrict__ bnms, unsigned long long* __restrict__ mask) {
  const int i = blockIdx.x;
  const int lane = threadIdx.x & 63;
  const int wv = threadIdx.x >> 6;
  const float4 bi = bnms[i];
  const float areai = fmaxf(bi.z - bi.x, 0.f) * fmaxf(bi.w - bi.y, 0.f);
  #pragma unroll
  for (int ww = 0; ww < 4; ++ww) {
    int wd = wv * 4 + ww;
    int j = wd * 64 + lane;
    bool bit = false;
    if (j < KPRE && j > i) {
      float4 bj = bnms[j];
      float areaj = fmaxf(bj.z - bj.x, 0.f) * fmaxf(bj.w - bj.y, 0.f);
      float ltx = fmaxf(bi.x, bj.x), lty = fmaxf(bi.y, bj.y);
      float rbx = fminf(bi.z, bj.z), rby = fminf(bi.w, bj.w);
      float iw = fmaxf(rbx - ltx, 0.f), ih = fmaxf(rby - lty, 0.f);
      float inter = iw * ih;
      float iou = inter / (areai + areaj - inter + 1e-7f);
      bit = iou > 0.5f;
    }
    unsigned long long mword = __ballot(bit);
    if (lane == 0) mask[(size_t)i * 16 + wd] = mword;
  }
}

// K5: greedy NMS: wave 0 scans from LDS; waves 1-3 prefetch next chunk.
__global__ __launch_bounds__(256)
void greedy_kernel(const unsigned long long* __restrict__ mask,
                   const float* __restrict__ sel_score,
                   const int* __restrict__ slabel,
                   const float4* __restrict__ braw,
                   float* __restrict__ out) {
  __shared__ ulonglong2 buf[2][GCHUNK * 8];       // 2 x 16 KB
  __shared__ int kept[NDET];
  __shared__ int s_done;
  const int t = threadIdx.x;
  const int lane = t & 63;
  const int wv = t >> 6;
  const ulonglong2* gm2 = reinterpret_cast<const ulonglong2*>(mask);
  constexpr int NCHUNK = (KPRE + GCHUNK - 1) / GCHUNK;   // 8

  unsigned long long kw = 0ull;
  #pragma unroll
  for (int w = 0; w < 16; ++w) {
    int j = w * 64 + lane;
    bool b = (j < KPRE) && (sel_score[j] > 0.f);
    unsigned long long mword = __ballot(b);
    if (lane == w) kw = mword;
  }
  if (t == 0) s_done = 0;

  {
    int rows = (KPRE < GCHUNK) ? KPRE : GCHUNK;
    int n2 = rows * 8;
    for (int k = t; k < n2; k += 256) buf[0][k] = gm2[k];
  }
  __syncthreads();

  int kc = 0;
  for (int c = 0; c < NCHUNK; ++c) {
    if (wv > 0 && c + 1 < NCHUNK) {
      int rows = KPRE - (c + 1) * GCHUNK;
      if (rows > GCHUNK) rows = GCHUNK;
      int n2 = rows * 8;
      size_t gbase = (size_t)(c + 1) * GCHUNK * 8;
      for (int k = t - 64; k < n2; k += 192) buf[(c + 1) & 1][k] = gm2[gbase + k];
    }
    if (wv == 0) {
      const unsigned long long* bb =
          reinterpret_cast<const unsigned long long*>(buf[c & 1]);
      int rows = KPRE - c * GCHUNK;
      if (rows > GCHUNK) rows = GCHUNK;
      unsigned long long curm = (lane < 16) ? bb[lane] : 0ull;
      for (int r = 0; r < rows; ++r) {
        unsigned long long nxt =
            (lane < 16 && r + 1 < rows) ? bb[(r + 1) * 16 + lane] : 0ull;
        int i = c * GCHUNK + r;
        unsigned long long kwv = __shfl(kw, i >> 6);
        if ((kwv >> (i & 63)) & 1ull) {
          if (lane == 0) kept[kc] = i;
          kw &= ~curm;
          ++kc;
          if (kc >= NDET) { if (lane == 0) s_done = 1; break; }
        }
        curm = nxt;
      }
    }
    __syncthreads();
    if (s_done) break;
  }

  if (wv == 0) {
    for (int q = lane; q < NDET; q += 64) {
      if (q < kc) {
        int i = kept[q];
        float4 b = braw[i];
        out[q * 4 + 0] = b.x; out[q * 4 + 1] = b.y;
        out[q * 4 + 2] = b.z; out[q * 4 + 3] = b.w;
        out[4 * NDET + q] = sel_score[i];
        out[5 * NDET + q] = (float)slabel[i];
      } else {
        out[q * 4 + 0] = 0.f; out[q * 4 + 1] = 0.f;
        out[q * 4 + 2] = 0.f; out[q * 4 + 3] = 0.f;
        out[4 * NDET + q] = 0.f;
        out[5 * NDET + q] = 0.f;
      }
    }
  }
}

extern "C" void kernel_launch(void* const* d_in, const int* in_sizes, int n_in,
                              void* d_out, int out_size, void* d_ws, size_t ws_size,
                              hipStream_t stream) {
  const float* logits = (const float*)d_in[0];
  const float* regr   = (const float*)d_in[1];
  const float* props  = (const float*)d_in[2];
  const int*   p_imh  = (const int*)d_in[3];
  const int*   p_imw  = (const int*)d_in[4];
  float* out = (float*)d_out;

  uint8_t* ws = (uint8_t*)d_ws;
  uint32_t* cnt  = (uint32_t*)(ws + OFF_CNT);
  uint16_t* rowmax = (uint16_t*)(ws + OFF_ROWMAX);
  unsigned long long* compact = (unsigned long long*)(ws + OFF_COMPACT);
  float*    sel_score = (float*)(ws + OFF_SSCORE);
  uint32_t* sel_gidx  = (uint32_t*)(ws + OFF_SGIDX);
  int*      slabel    = (int*)(ws + OFF_SLABEL);
  float4*   braw      = (float4*)(ws + OFF_BRAW);
  float4*   bnms      = (float4*)(ws + OFF_BNMS);
  unsigned long long* mask = (unsigned long long*)(ws + OFF_MASK);
  uint16_t* cpart     = (uint16_t*)(ws + OFF_CPART);

  pass1_kernel<<<P1BLK, 256, 0, stream>>>(
      logits, regr, props, p_imh, p_imw, rowmax, cpart, cnt);
  refine_kernel<<<R2BLK, 1024, 0, stream>>>(
      logits, regr, props, p_imh, p_imw, rowmax, cpart, cnt, compact);
  rank_prep_kernel<<<RNKB, 1024, 0, stream>>>(compact, cnt, regr, props, p_imh, p_imw,
                                              sel_score, sel_gidx, slabel, braw, bnms);
  iou_kernel<<<KPRE, 256, 0, stream>>>(bnms, mask);
  greedy_kernel<<<1, 256, 0, stream>>>(mask, sel_score, slabel, braw, out);
}

// Round 22
// 91.819 us; speedup vs baseline: 1.7562x; 1.0035x over previous
//
#include <hip/hip_runtime.h>
#include <cstdint>

#define NROWS 50000
#define NCLS  91
#define KPRE  1000
#define NDET  100
#define CAP   4096
#define BIN_OFF 62770u      // bin = (bits>>14) - 62770; scores (0.05,1] -> [1,2254]
#define LOGCLAMP 4.135166556742356f
#define P1BLK 3125          // 3125*256 threads = 50000 rows * 16
#define R2BLK 196           // 196 blocks * 256 rows = 50176 >= 50000
#define R2ROWS 256          // rows per refine block
#define NFINE 256           // fine bins inside the crossing coarse bucket
#define NU4   6250          // rowmax as uint4: 50000*2B / 16B
#define CPS   3136          // coarse-partial stride (u16) per bucket row
#define CP4   3528          // 9 * 3136/8 uint4 in cpart
#define GCHUNK 128          // greedy: mask rows per LDS chunk
#define RNKB  4             // rank blocks: 4*1024 = CAP keys, 1/thread

// ---- workspace layout (bytes) ----
constexpr size_t OFF_CNT     = 0;        // [1]=compact count
constexpr size_t OFF_ROWMAX  = 64;       // 50000*2 (16B-aligned)
constexpr size_t OFF_COMPACT = 100096;   // CAP*8 = 32768
constexpr size_t OFF_SSCORE  = 132864;   // 1024*4
constexpr size_t OFF_SGIDX   = 136960;   // 1024*4
constexpr size_t OFF_SLABEL  = 141056;   // 1024*4
constexpr size_t OFF_BRAW    = 145152;   // 16384
constexpr size_t OFF_BNMS    = 161536;   // 16384
constexpr size_t OFF_MASK    = 177920;   // 1000*16*8 = 128000
constexpr size_t OFF_CPART   = 305920;   // 9*3136*2 = 56448 -> end ~362 KB

// DPP rotate-reduce within a 16-lane group (one DPP "row"): row_ror:n.
// Full-rate VALU, no LDS/ds_bpermute latency. ctrl: 0x120+n = row_ror n.
template <int CTRL>
__device__ __forceinline__ float dpp_rorf(float x) {
  int v = __builtin_amdgcn_update_dpp(0, __float_as_int(x), CTRL, 0xF, 0xF, true);
  return __int_as_float(v);
}
template <int CTRL>
__device__ __forceinline__ int dpp_rori(int x) {
  return __builtin_amdgcn_update_dpp(0, x, CTRL, 0xF, 0xF, true);
}
__device__ __forceinline__ float grp16_max(float m) {
  m = fmaxf(m, dpp_rorf<0x128>(m));   // ror 8
  m = fmaxf(m, dpp_rorf<0x124>(m));   // ror 4
  m = fmaxf(m, dpp_rorf<0x122>(m));   // ror 2
  m = fmaxf(m, dpp_rorf<0x121>(m));   // ror 1
  return m;
}
__device__ __forceinline__ float grp16_sum(float s) {
  s += dpp_rorf<0x128>(s);
  s += dpp_rorf<0x124>(s);
  s += dpp_rorf<0x122>(s);
  s += dpp_rorf<0x121>(s);
  return s;
}
__device__ __forceinline__ int grp16_imax(int v) {
  v = max(v, dpp_rori<0x128>(v));
  v = max(v, dpp_rori<0x124>(v));
  v = max(v, dpp_rori<0x122>(v));
  v = max(v, dpp_rori<0x121>(v));
  return v;
}

__device__ __forceinline__ bool decode_box(int row, int c,
    const float* __restrict__ regr, const float* __restrict__ props,
    float W, float H, float4& b) {
  const float4 rr = *reinterpret_cast<const float4*>(regr + (size_t)row * (NCLS * 4) + c * 4);
  const float4 pp = *reinterpret_cast<const float4*>(props + (size_t)row * 4);
  float pw = pp.z - pp.x, ph = pp.w - pp.y;
  float cx = pp.x + 0.5f * pw, cy = pp.y + 0.5f * ph;
  float dx = rr.x / 10.0f, dy = rr.y / 10.0f;
  float dw = fminf(rr.z / 5.0f, LOGCLAMP);
  float dh = fminf(rr.w / 5.0f, LOGCLAMP);
  float pcx = dx * pw + cx, pcy = dy * ph + cy;
  float ppw = expf(dw) * pw, pph = expf(dh) * ph;
  float x1 = fminf(fmaxf(pcx - 0.5f * ppw, 0.f), W);
  float y1 = fminf(fmaxf(pcy - 0.5f * pph, 0.f), H);
  float x2 = fminf(fmaxf(pcx + 0.5f * ppw, 0.f), W);
  float y2 = fminf(fmaxf(pcy + 0.5f * pph, 0.f), H);
  b = make_float4(x1, y1, x2, y2);
  return (x2 - x1 >= 0.01f) && (y2 - y1 >= 0.01f);
}

__device__ __forceinline__ bool decode_box_v(const float4& rr, const float4& pp,
                                             float W, float H, float4& b) {
  float pw = pp.z - pp.x, ph = pp.w - pp.y;
  float cx = pp.x + 0.5f * pw, cy = pp.y + 0.5f * ph;
  float dx = rr.x / 10.0f, dy = rr.y / 10.0f;
  float dw = fminf(rr.z / 5.0f, LOGCLAMP);
  float dh = fminf(rr.w / 5.0f, LOGCLAMP);
  float pcx = dx * pw + cx, pcy = dy * ph + cy;
  float ppw = expf(dw) * pw, pph = expf(dh) * ph;
  float x1 = fminf(fmaxf(pcx - 0.5f * ppw, 0.f), W);
  float y1 = fminf(fmaxf(pcy - 0.5f * pph, 0.f), H);
  float x2 = fminf(fmaxf(pcx + 0.5f * ppw, 0.f), W);
  float y2 = fminf(fmaxf(pcy + 0.5f * pph, 0.f), H);
  b = make_float4(x1, y1, x2, y2);
  return (x2 - x1 >= 0.01f) && (y2 - y1 >= 0.01f);
}

// K1: 16 threads/row, 6 classes/thread. DPP rotate-reduce (no ds shuffles).
// props prefetched; batched conditional regr loads. Emits rowmax + cpart.
__global__ __launch_bounds__(256)
void pass1_kernel(const float* __restrict__ logits,
                  const float* __restrict__ regr,
                  const float* __restrict__ props,
                  const int* __restrict__ p_imh,
                  const int* __restrict__ p_imw,
                  uint16_t* __restrict__ rowmax,
                  uint16_t* __restrict__ cpart,
                  uint32_t* __restrict__ cnt) {
  __shared__ uint32_t lds9[9];
  const int t = threadIdx.x;
  if (blockIdx.x == 0 && t == 0) cnt[1] = 0;
  if (t < 9) lds9[t] = 0;
  __syncthreads();

  const int gt  = blockIdx.x * 256 + t;
  const int row = gt >> 4;
  const int sub = gt & 15;
  const float* lr = logits + (size_t)row * NCLS;
  const float4 pp = *reinterpret_cast<const float4*>(props + (size_t)row * 4);
  const float W = (float)(*p_imw), H = (float)(*p_imh);

  float x[6];
  #pragma unroll
  for (int j = 0; j < 6; ++j) {
    int c = sub + 16 * j;
    x[j] = (c < NCLS) ? lr[c] : -INFINITY;
  }
  float m = x[0];
  #pragma unroll
  for (int j = 1; j < 6; ++j) m = fmaxf(m, x[j]);
  m = grp16_max(m);
  float e[6]; float s = 0.f;
  #pragma unroll
  for (int j = 0; j < 6; ++j) {
    e[j] = (sub + 16 * j < NCLS) ? expf(x[j] - m) : 0.f;
    s += e[j];
  }
  s = grp16_sum(s);

  const float4* rr4 = reinterpret_cast<const float4*>(regr) + (size_t)row * NCLS;
  float score[6]; bool ok[6]; float4 rrv[6];
  #pragma unroll
  for (int j = 0; j < 6; ++j) {
    int c = sub + 16 * j;
    score[j] = e[j] / s;
    ok[j] = (c >= 1) && (c < NCLS) && (score[j] > 0.05f);
    rrv[j] = ok[j] ? rr4[c] : make_float4(0.f, 0.f, 0.f, 0.f);
  }
  int maxbin = 0;
  #pragma unroll
  for (int j = 0; j < 6; ++j) {
    if (ok[j]) {
      float4 b;
      if (decode_box_v(rrv[j], pp, W, H, b)) {
        uint32_t bin = (__float_as_uint(score[j]) >> 14) - BIN_OFF;
        if ((int)bin > maxbin) maxbin = (int)bin;
      }
    }
  }
  maxbin = grp16_imax(maxbin);
  if (sub == 0) {
    rowmax[row] = (uint16_t)maxbin;
    if (maxbin > 0) atomicAdd(&lds9[maxbin >> 8], 1u);   // bucket 0..8
  }
  __syncthreads();
  if (t < 9) cpart[(size_t)t * CPS + blockIdx.x] = (uint16_t)lds9[t];
  if (blockIdx.x < 9 && t < CPS - P1BLK)
    cpart[(size_t)blockIdx.x * CPS + P1BLK + t] = 0;
}

// K2: 196 blocks x 1024 (256 rows each). Coarse from cpart, ONE fine pass
// over rowmax, exact cut (redundant per block), refine rows. Same DPP
// reductions as pass1 (arithmetic must match bit-for-bit).
__global__ __launch_bounds__(1024)
void refine_kernel(const float* __restrict__ logits,
                   const float* __restrict__ regr,
                   const float* __restrict__ props,
                   const int* __restrict__ p_imh,
                   const int* __restrict__ p_imw,
                   const uint16_t* __restrict__ rowmax,
                   const uint16_t* __restrict__ cpart,
                   uint32_t* __restrict__ cnt,
                   unsigned long long* __restrict__ compact) {
  __shared__ uint32_t fine[NFINE + 1];
  __shared__ uint32_t lds9[9];
  __shared__ uint32_t s_cut;
  const int t = threadIdx.x;
  if (t < 9) lds9[t] = 0;
  if (t < NFINE + 1) fine[t] = 0;
  if (t == 0) s_cut = 0xFFFFFFFFu;
  __syncthreads();

  const uint4* cp4 = reinterpret_cast<const uint4*>(cpart);
  for (int k = t; k < CP4; k += 1024) {
    uint4 v = cp4[k];
    uint32_t ssum = (v.x & 0xffffu) + (v.x >> 16) + (v.y & 0xffffu) + (v.y >> 16) +
                    (v.z & 0xffffu) + (v.z >> 16) + (v.w & 0xffffu) + (v.w >> 16);
    if (ssum) atomicAdd(&lds9[k / 392], ssum);     // 392 uint4 per bucket row
  }
  __syncthreads();
  uint32_t sfx[10];
  sfx[9] = 0;
  #pragma unroll
  for (int q = 8; q >= 0; --q) sfx[q] = sfx[q + 1] + lds9[q];
  const uint32_t total = sfx[0];
  uint32_t cut;
  if (total == 0) {
    cut = 0xFFFFFFFFu;
  } else {
    const uint32_t target = total < (uint32_t)KPRE ? total : (uint32_t)KPRE;
    int Bc = 0;
    uint32_t S_hi = 0;
    #pragma unroll
    for (int q = 8; q >= 0; --q) {
      if (sfx[q] >= target && sfx[q + 1] < target) { Bc = q; S_hi = sfx[q + 1]; }
    }
    const uint4* r128 = reinterpret_cast<const uint4*>(rowmax);
    for (int k = t; k < NU4; k += 1024) {
      uint4 v = r128[k];
      #pragma unroll
      for (int w = 0; w < 4; ++w) {
        uint32_t u = (w == 0) ? v.x : (w == 1) ? v.y : (w == 2) ? v.z : v.w;
        uint32_t a = u & 0xffffu, b = u >> 16;
        if (a && (a >> 8) == (uint32_t)Bc) atomicAdd(&fine[a & 255u], 1u);
        if (b && (b >> 8) == (uint32_t)Bc) atomicAdd(&fine[b & 255u], 1u);
      }
    }
    __syncthreads();
    for (int off = 1; off < NFINE; off <<= 1) {
      uint32_t add = (t < NFINE && t + off < NFINE) ? fine[t + off] : 0;
      __syncthreads();
      if (t < NFINE) fine[t] += add;
      __syncthreads();
    }
    if (t < NFINE) {
      uint32_t hi = S_hi + fine[t];
      uint32_t hin = S_hi + ((t < NFINE - 1) ? fine[t + 1] : 0);
      if (hi >= target && hin < target) s_cut = ((uint32_t)Bc << 8) + (uint32_t)t;
    }
    __syncthreads();
    cut = s_cut;
  }

  // ---- refine this block's 256 rows (threads 0..255; op-for-op pass1 math) ----
  const int lane = t & 63;
  const int g16 = lane >> 4;
  const int sub = lane & 15;
  const float W = (float)(*p_imw), H = (float)(*p_imh);
  const int base = blockIdx.x * R2ROWS;
  const int myrow0 = base + t;
  bool qual = (t < R2ROWS) && (myrow0 < NROWS) && ((uint32_t)rowmax[myrow0] >= cut);
  unsigned long long bm = __ballot(qual);
  if (!bm) return;
  const int waveBase = base + (t & ~63);
  while (bm) {
    int bsel[4];
    #pragma unroll
    for (int k = 0; k < 4; ++k) {
      bsel[k] = bm ? (__ffsll((unsigned long long)bm) - 1) : -1;
      if (bm) bm &= bm - 1;
    }
    const int myb = bsel[g16];
    const int row = waveBase + (myb >= 0 ? myb : 0);
    const float* lr = logits + (size_t)row * NCLS;
    float x[6];
    #pragma unroll
    for (int j = 0; j < 6; ++j) {
      int c = sub + 16 * j;
      x[j] = (c < NCLS) ? lr[c] : -INFINITY;
    }
    float m = x[0];
    #pragma unroll
    for (int j = 1; j < 6; ++j) m = fmaxf(m, x[j]);
    m = grp16_max(m);
    float e[6]; float s = 0.f;
    #pragma unroll
    for (int j = 0; j < 6; ++j) {
      e[j] = (sub + 16 * j < NCLS) ? expf(x[j] - m) : 0.f;
      s += e[j];
    }
    s = grp16_sum(s);
    if (myb >= 0) {
      #pragma unroll
      for (int j = 0; j < 6; ++j) {
        int c = sub + 16 * j;
        if (c >= 1 && c < NCLS) {
          float score = e[j] / s;
          if (score > 0.05f) {
            float4 bb;
            if (decode_box(row, c, regr, props, W, H, bb)) {
              uint32_t bits = __float_as_uint(score);
              uint32_t bin = (bits >> 14) - BIN_OFF;
              if (bin >= cut) {
                uint32_t pos = atomicAdd(&cnt[1], 1u);
                if (pos < CAP) {
                  uint32_t gidx = (uint32_t)row * 90u + (uint32_t)(c - 1);
                  compact[pos] = ((unsigned long long)bits << 32) |
                                 (unsigned long long)(0xFFFFFFFFu - gidx);
                }
              }
            }
          }
        }
      }
    }
  }
}

// K3: 4 blocks x 1024. Rank-based selection (unroll-16 LDS broadcast loop).
__global__ __launch_bounds__(1024)
void rank_prep_kernel(const unsigned long long* __restrict__ compact,
                      const uint32_t* __restrict__ cnt,
                      const float* __restrict__ regr, const float* __restrict__ props,
                      const int* __restrict__ p_imh, const int* __restrict__ p_imw,
                      float* __restrict__ sel_score, uint32_t* __restrict__ sel_gidx,
                      int* __restrict__ slabel, float4* __restrict__ braw,
                      float4* __restrict__ bnms) {
  __shared__ unsigned long long keys[CAP];
  const int t = threadIdx.x;
  const int M = (int)(cnt[1] < (uint32_t)CAP ? cnt[1] : (uint32_t)CAP);
  for (int i = t; i < M; i += 1024) keys[i] = compact[i];
  __syncthreads();

  const int ii = blockIdx.x * 1024 + t;
  const unsigned long long kk = (ii < M) ? keys[ii] : 0xFFFFFFFFFFFFFFFFull;
  int r = 0;
  int j = 0;
  const int M16 = M & ~15;
  #pragma unroll 1
  for (; j < M16; j += 16) {
    int acc = 0;
    #pragma unroll
    for (int u = 0; u < 16; ++u) acc += (keys[j + u] > kk);
    r += acc;
  }
  for (; j < M; ++j) r += (keys[j] > kk);

  const float W = (float)(*p_imw), H = (float)(*p_imh);
  const float offmul = (float)(*p_imw + *p_imh + 2);
  if (ii < M && r < KPRE) {
    float sc = __uint_as_float((uint32_t)(kk >> 32));
    uint32_t g = 0xFFFFFFFFu - (uint32_t)kk;
    sel_score[r] = sc;
    sel_gidx[r] = g;
    int row = (int)(g / 90u);
    int c   = (int)(g % 90u) + 1;
    float4 b;
    decode_box(row, c, regr, props, W, H, b);
    braw[r] = b;
    float offv = (float)c * offmul;
    bnms[r] = make_float4(b.x + offv, b.y + offv, b.z + offv, b.w + offv);
    slabel[r] = c;
  }
  if (blockIdx.x == 0 && t >= M && t < KPRE) {
    sel_score[t] = -1.f;
    sel_gidx[t] = 0xFFFFFFFFu;
    braw[t] = make_float4(0, 0, 0, 0);
    bnms[t] = make_float4(0, 0, 0, 0);
    slabel[t] = 0;
  }
}

// K4: 1000 blocks x 256: 4 waves x 4 mask-words each.
__global__ __launch_bounds__(256)
void iou_kernel(const float4* __restrict__ bnms, unsigned long long* __restrict__ mask) {
  const int i = blockIdx.x;
  const int lane = threadIdx.x & 63;
  const int wv = threadIdx.x >> 6;
  const float4 bi = bnms[i];
  const float areai = fmaxf(bi.z - bi.x, 0.f) * fmaxf(bi.w - bi.y, 0.f);
  #pragma unroll
  for (int ww = 0; ww < 4; ++ww) {
    int wd = wv * 4 + ww;
    int j = wd * 64 + lane;
    bool bit = false;
    if (j < KPRE && j > i) {
      float4 bj = bnms[j];
      float areaj = fmaxf(bj.z - bj.x, 0.f) * fmaxf(bj.w - bj.y, 0.f);
      float ltx = fmaxf(bi.x, bj.x), lty = fmaxf(bi.y, bj.y);
      float rbx = fminf(bi.z, bj.z), rby = fminf(bi.w, bj.w);
      float iw = fmaxf(rbx - ltx, 0.f), ih = fmaxf(rby - lty, 0.f);
      float inter = iw * ih;
      float iou = inter / (areai + areaj - inter + 1e-7f);
      bit = iou > 0.5f;
    }
    unsigned long long mword = __ballot(bit);
    if (lane == 0) mask[(size_t)i * 16 + wd] = mword;
  }
}

// K5: greedy NMS: wave 0 scans from LDS; waves 1-3 prefetch next chunk.
__global__ __launch_bounds__(256)
void greedy_kernel(const unsigned long long* __restrict__ mask,
                   const float* __restrict__ sel_score,
                   const int* __restrict__ slabel,
                   const float4* __restrict__ braw,
                   float* __restrict__ out) {
  __shared__ ulonglong2 buf[2][GCHUNK * 8];       // 2 x 16 KB
  __shared__ int kept[NDET];
  __shared__ int s_done;
  const int t = threadIdx.x;
  const int lane = t & 63;
  const int wv = t >> 6;
  const ulonglong2* gm2 = reinterpret_cast<const ulonglong2*>(mask);
  constexpr int NCHUNK = (KPRE + GCHUNK - 1) / GCHUNK;   // 8

  unsigned long long kw = 0ull;
  #pragma unroll
  for (int w = 0; w < 16; ++w) {
    int j = w * 64 + lane;
    bool b = (j < KPRE) && (sel_score[j] > 0.f);
    unsigned long long mword = __ballot(b);
    if (lane == w) kw = mword;
  }
  if (t == 0) s_done = 0;

  {
    int rows = (KPRE < GCHUNK) ? KPRE : GCHUNK;
    int n2 = rows * 8;
    for (int k = t; k < n2; k += 256) buf[0][k] = gm2[k];
  }
  __syncthreads();

  int kc = 0;
  for (int c = 0; c < NCHUNK; ++c) {
    if (wv > 0 && c + 1 < NCHUNK) {
      int rows = KPRE - (c + 1) * GCHUNK;
      if (rows > GCHUNK) rows = GCHUNK;
      int n2 = rows * 8;
      size_t gbase = (size_t)(c + 1) * GCHUNK * 8;
      for (int k = t - 64; k < n2; k += 192) buf[(c + 1) & 1][k] = gm2[gbase + k];
    }
    if (wv == 0) {
      const unsigned long long* bb =
          reinterpret_cast<const unsigned long long*>(buf[c & 1]);
      int rows = KPRE - c * GCHUNK;
      if (rows > GCHUNK) rows = GCHUNK;
      unsigned long long curm = (lane < 16) ? bb[lane] : 0ull;
      for (int r = 0; r < rows; ++r) {
        unsigned long long nxt =
            (lane < 16 && r + 1 < rows) ? bb[(r + 1) * 16 + lane] : 0ull;
        int i = c * GCHUNK + r;
        unsigned long long kwv = __shfl(kw, i >> 6);
        if ((kwv >> (i & 63)) & 1ull) {
          if (lane == 0) kept[kc] = i;
          kw &= ~curm;
          ++kc;
          if (kc >= NDET) { if (lane == 0) s_done = 1; break; }
        }
        curm = nxt;
      }
    }
    __syncthreads();
    if (s_done) break;
  }

  if (wv == 0) {
    for (int q = lane; q < NDET; q += 64) {
      if (q < kc) {
        int i = kept[q];
        float4 b = braw[i];
        out[q * 4 + 0] = b.x; out[q * 4 + 1] = b.y;
        out[q * 4 + 2] = b.z; out[q * 4 + 3] = b.w;
        out[4 * NDET + q] = sel_score[i];
        out[5 * NDET + q] = (float)slabel[i];
      } else {
        out[q * 4 + 0] = 0.f; out[q * 4 + 1] = 0.f;
        out[q * 4 + 2] = 0.f; out[q * 4 + 3] = 0.f;
        out[4 * NDET + q] = 0.f;
        out[5 * NDET + q] = 0.f;
      }
    }
  }
}

extern "C" void kernel_launch(void* const* d_in, const int* in_sizes, int n_in,
                              void* d_out, int out_size, void* d_ws, size_t ws_size,
                              hipStream_t stream) {
  const float* logits = (const float*)d_in[0];
  const float* regr   = (const float*)d_in[1];
  const float* props  = (const float*)d_in[2];
  const int*   p_imh  = (const int*)d_in[3];
  const int*   p_imw  = (const int*)d_in[4];
  float* out = (float*)d_out;

  uint8_t* ws = (uint8_t*)d_ws;
  uint32_t* cnt  = (uint32_t*)(ws + OFF_CNT);
  uint16_t* rowmax = (uint16_t*)(ws + OFF_ROWMAX);
  unsigned long long* compact = (unsigned long long*)(ws + OFF_COMPACT);
  float*    sel_score = (float*)(ws + OFF_SSCORE);
  uint32_t* sel_gidx  = (uint32_t*)(ws + OFF_SGIDX);
  int*      slabel    = (int*)(ws + OFF_SLABEL);
  float4*   braw      = (float4*)(ws + OFF_BRAW);
  float4*   bnms      = (float4*)(ws + OFF_BNMS);
  unsigned long long* mask = (unsigned long long*)(ws + OFF_MASK);
  uint16_t* cpart     = (uint16_t*)(ws + OFF_CPART);

  pass1_kernel<<<P1BLK, 256, 0, stream>>>(
      logits, regr, props, p_imh, p_imw, rowmax, cpart, cnt);
  refine_kernel<<<R2BLK, 1024, 0, stream>>>(
      logits, regr, props, p_imh, p_imw, rowmax, cpart, cnt, compact);
  rank_prep_kernel<<<RNKB, 1024, 0, stream>>>(compact, cnt, regr, props, p_imh, p_imw,
                                              sel_score, sel_gidx, slabel, braw, bnms);
  iou_kernel<<<KPRE, 256, 0, stream>>>(bnms, mask);
  greedy_kernel<<<1, 256, 0, stream>>>(mask, sel_score, slabel, braw, out);
}